// Round 4
// baseline (204.233 us; speedup 1.0000x reference)
//
#include <hip/hip_runtime.h>
#include <hip/hip_bf16.h>

// Problem constants (AFTLocalAutoregressive): T=2048, B=2, D=512, S=32
#define TT 2048
#define BB 2
#define DD 512
#define BD (BB*DD)        // 1024 columns (b,d flattened)
#define SS 32
#define MR (TT*BB)        // 4096 GEMM rows; m = 2t + b
#define NE (TT*BB*DD)     // 2097152 elements per (T,B,D) tensor
#define CH 32             // t-chunk size for scan/window (== one 64-row m-tile)

typedef __bf16 bf16x8 __attribute__((ext_vector_type(8)));
typedef float f32x4 __attribute__((ext_vector_type(4)));

__device__ __forceinline__ void async_copy16(void* lds, const void* gptr) {
    __builtin_amdgcn_global_load_lds(
        (const __attribute__((address_space(1))) void*)gptr,
        (__attribute__((address_space(3))) void*)lds,
        16, 0, 0);
}

// Stage one 64x32 fp32 tile as bf16 into LDS (k-quad-major: kq*1024 + row*16).
// 256 threads: row = tid&63, kq = tid>>6. RNE cast == previous cast kernel.
__device__ __forceinline__ void stage_cvt(
    const float* __restrict__ src, int row0, int k0,
    char* lds, int row, int kq)
{
    const float* p = src + (size_t)(row0 + row) * DD + k0 + kq * 8;
    float4 f0 = *(const float4*)p;
    float4 f1 = *(const float4*)(p + 4);
    union { __hip_bfloat16 h[8]; int4 v; } u;
    u.h[0] = __float2bfloat16(f0.x); u.h[1] = __float2bfloat16(f0.y);
    u.h[2] = __float2bfloat16(f0.z); u.h[3] = __float2bfloat16(f0.w);
    u.h[4] = __float2bfloat16(f1.x); u.h[5] = __float2bfloat16(f1.y);
    u.h[6] = __float2bfloat16(f1.z); u.h[7] = __float2bfloat16(f1.w);
    *(int4*)(lds + kq * 1024 + row * 16) = u.v;
}

// ---------------------------------------------------------------------------
// z=0: q = query@Wq^T + bq  (fp32 out)
// z=1: k,v projections fused; epilogue writes ek=exp(k), ekv=ek*v AND the
//      per-chunk column sums part_d/part_n (this block == t-chunk blockIdx.y).
// 64x64 tile, 256 threads (4 waves, 2x2 subtiles of 16x16), BK=32.
// max_logit is dropped: cancels exactly in num/den; |k|<~2.5 so exp is safe.
// ---------------------------------------------------------------------------
__global__ __launch_bounds__(256) void gemm_qkv(
    const float* __restrict__ query, const float* __restrict__ key,
    const float* __restrict__ value,
    const float* __restrict__ Wq, const float* __restrict__ Wk,
    const float* __restrict__ Wv,
    const float* __restrict__ bq, const float* __restrict__ bk,
    const float* __restrict__ bv,
    float* __restrict__ qout, float* __restrict__ ek, float* __restrict__ ekv,
    float* __restrict__ part_d, float* __restrict__ part_n)
{
    __shared__ char smem[16384];
    const int tid = threadIdx.x;
    const int lane = tid & 63;
    const int wv = tid >> 6;
    const int wave_m = wv >> 1, wave_n = wv & 1;
    const int m0 = blockIdx.y * 64, n0 = blockIdx.x * 64;
    const int kq = lane >> 4, rr = lane & 15;
    const int srow = tid & 63, skq = tid >> 6;

    if (blockIdx.z == 0) {
        f32x4 acc[2][2] = {};
        for (int k0 = 0; k0 < DD; k0 += 32) {
            __syncthreads();
            stage_cvt(query, m0, k0, smem, srow, skq);
            stage_cvt(Wq, n0, k0, smem + 4096, srow, skq);
            __syncthreads();
            bf16x8 a0 = *(const bf16x8*)&smem[kq*1024 + (wave_m*32 +  0 + rr)*16];
            bf16x8 a1 = *(const bf16x8*)&smem[kq*1024 + (wave_m*32 + 16 + rr)*16];
            bf16x8 b0 = *(const bf16x8*)&smem[4096 + kq*1024 + (wave_n*32 +  0 + rr)*16];
            bf16x8 b1 = *(const bf16x8*)&smem[4096 + kq*1024 + (wave_n*32 + 16 + rr)*16];
            acc[0][0] = __builtin_amdgcn_mfma_f32_16x16x32_bf16(a0, b0, acc[0][0], 0, 0, 0);
            acc[0][1] = __builtin_amdgcn_mfma_f32_16x16x32_bf16(a0, b1, acc[0][1], 0, 0, 0);
            acc[1][0] = __builtin_amdgcn_mfma_f32_16x16x32_bf16(a1, b0, acc[1][0], 0, 0, 0);
            acc[1][1] = __builtin_amdgcn_mfma_f32_16x16x32_bf16(a1, b1, acc[1][1], 0, 0, 0);
        }
        #pragma unroll
        for (int ms = 0; ms < 2; ++ms)
            #pragma unroll
            for (int ns = 0; ns < 2; ++ns) {
                int n = n0 + wave_n*32 + ns*16 + rr;
                float bn = bq[n];
                #pragma unroll
                for (int r = 0; r < 4; ++r) {
                    int m = m0 + wave_m*32 + ms*16 + kq*4 + r;
                    qout[(size_t)m * DD + n] = acc[ms][ns][r] + bn;
                }
            }
    } else {
        f32x4 acck[2][2] = {}, accv[2][2] = {};
        for (int k0 = 0; k0 < DD; k0 += 32) {
            __syncthreads();
            stage_cvt(key,   m0, k0, smem,         srow, skq);
            stage_cvt(Wk,    n0, k0, smem + 4096,  srow, skq);
            stage_cvt(value, m0, k0, smem + 8192,  srow, skq);
            stage_cvt(Wv,    n0, k0, smem + 12288, srow, skq);
            __syncthreads();
            bf16x8 ak0 = *(const bf16x8*)&smem[kq*1024 + (wave_m*32 +  0 + rr)*16];
            bf16x8 ak1 = *(const bf16x8*)&smem[kq*1024 + (wave_m*32 + 16 + rr)*16];
            bf16x8 bk0 = *(const bf16x8*)&smem[4096 + kq*1024 + (wave_n*32 +  0 + rr)*16];
            bf16x8 bk1 = *(const bf16x8*)&smem[4096 + kq*1024 + (wave_n*32 + 16 + rr)*16];
            bf16x8 av0 = *(const bf16x8*)&smem[8192 + kq*1024 + (wave_m*32 +  0 + rr)*16];
            bf16x8 av1 = *(const bf16x8*)&smem[8192 + kq*1024 + (wave_m*32 + 16 + rr)*16];
            bf16x8 bv0 = *(const bf16x8*)&smem[12288 + kq*1024 + (wave_n*32 +  0 + rr)*16];
            bf16x8 bv1 = *(const bf16x8*)&smem[12288 + kq*1024 + (wave_n*32 + 16 + rr)*16];
            acck[0][0] = __builtin_amdgcn_mfma_f32_16x16x32_bf16(ak0, bk0, acck[0][0], 0, 0, 0);
            acck[0][1] = __builtin_amdgcn_mfma_f32_16x16x32_bf16(ak0, bk1, acck[0][1], 0, 0, 0);
            acck[1][0] = __builtin_amdgcn_mfma_f32_16x16x32_bf16(ak1, bk0, acck[1][0], 0, 0, 0);
            acck[1][1] = __builtin_amdgcn_mfma_f32_16x16x32_bf16(ak1, bk1, acck[1][1], 0, 0, 0);
            accv[0][0] = __builtin_amdgcn_mfma_f32_16x16x32_bf16(av0, bv0, accv[0][0], 0, 0, 0);
            accv[0][1] = __builtin_amdgcn_mfma_f32_16x16x32_bf16(av0, bv1, accv[0][1], 0, 0, 0);
            accv[1][0] = __builtin_amdgcn_mfma_f32_16x16x32_bf16(av1, bv0, accv[1][0], 0, 0, 0);
            accv[1][1] = __builtin_amdgcn_mfma_f32_16x16x32_bf16(av1, bv1, accv[1][1], 0, 0, 0);
        }
        // epilogue: ek/ekv stores + per-chunk column sums (split by b = m&1 = r&1)
        float sd[2][2] = {{0.f,0.f},{0.f,0.f}};   // [ns][parity]
        float sn[2][2] = {{0.f,0.f},{0.f,0.f}};
        #pragma unroll
        for (int ms = 0; ms < 2; ++ms)
            #pragma unroll
            for (int ns = 0; ns < 2; ++ns) {
                int n = n0 + wave_n*32 + ns*16 + rr;
                float bkn = bk[n], bvn = bv[n];
                #pragma unroll
                for (int r = 0; r < 4; ++r) {
                    int m = m0 + wave_m*32 + ms*16 + kq*4 + r;
                    float e  = expf(acck[ms][ns][r] + bkn);
                    float nv = e * (accv[ms][ns][r] + bvn);
                    ek[(size_t)m * DD + n]  = e;
                    ekv[(size_t)m * DD + n] = nv;
                    sd[ns][r & 1] += e;
                    sn[ns][r & 1] += nv;
                }
            }
        // reduce over the 4 kq groups (lane bits 4,5)
        #pragma unroll
        for (int ns = 0; ns < 2; ++ns)
            #pragma unroll
            for (int par = 0; par < 2; ++par) {
                sd[ns][par] += __shfl_xor(sd[ns][par], 16, 64);
                sd[ns][par] += __shfl_xor(sd[ns][par], 32, 64);
                sn[ns][par] += __shfl_xor(sn[ns][par], 16, 64);
                sn[ns][par] += __shfl_xor(sn[ns][par], 32, 64);
            }
        __syncthreads();                       // smem free for reuse
        float* red = (float*)smem;             // red[which(4)][wave_m(2)][64]
        if (lane < 16) {
            #pragma unroll
            for (int ns = 0; ns < 2; ++ns) {
                int c = wave_n*32 + ns*16 + rr;
                red[(0*2 + wave_m)*64 + c] = sd[ns][0];
                red[(1*2 + wave_m)*64 + c] = sd[ns][1];
                red[(2*2 + wave_m)*64 + c] = sn[ns][0];
                red[(3*2 + wave_m)*64 + c] = sn[ns][1];
            }
        }
        __syncthreads();
        {
            int which = tid >> 6;              // 0: d,b0  1: d,b1  2: n,b0  3: n,b1
            int c = tid & 63;
            float s = red[(which*2 + 0)*64 + c] + red[(which*2 + 1)*64 + c];
            int b = which & 1;
            float* dst = (which < 2) ? part_d : part_n;
            dst[(size_t)blockIdx.y * BD + b*512 + n0 + c] = s;
        }
    }
}

// Fused: chunk-prefix seed + streaming scan + sliding window (register ring)
// + sigmoid gate + bf16 cast.  grid (BD/256, T/CH) = (4, 64).
__global__ __launch_bounds__(256) void fused_window(
    const float* __restrict__ q, const float* __restrict__ ek,
    const float* __restrict__ ekv, const float* __restrict__ part_d,
    const float* __restrict__ part_n, const float* __restrict__ pb,
    __hip_bfloat16* __restrict__ yb)
{
    __shared__ float wl[CH][SS];          // 4 KB: wexp for this t-chunk
    const int tid = threadIdx.x;
    const int col = blockIdx.x * 256 + tid;
    const int chunk = blockIdx.y;
    const int t0 = chunk * CH;

    // w[t_local][j] = valid * exp(pb[t, t-31+j])
    #pragma unroll
    for (int i = 0; i < (CH * SS) / 256; ++i) {
        int idx = tid + i * 256;
        int tl = idx >> 5, j = idx & 31;
        int t = t0 + tl;
        int u = t - (SS - 1) + j;
        float w = 0.f;
        if (u >= 0) w = expf(pb[(size_t)t * TT + u]);
        wl[tl][j] = w;
    }
    __syncthreads();

    float ring_d[32], ring_n[32];
    float cs_d = 0.f, cs_n = 0.f;
    const bool hasp = (chunk > 0);
    if (hasp) {
        float pref_d = 0.f, pref_n = 0.f;
        for (int p = 0; p < chunk; ++p) {
            pref_d += part_d[(size_t)p * BD + col];
            pref_n += part_n[(size_t)p * BD + col];
        }
        float ssd = 0.f, ssn = 0.f;
        #pragma unroll
        for (int i = 0; i < 32; ++i) {     // prefill ring with t0-32 .. t0-1
            size_t off = (size_t)(t0 - 32 + i) * BD + col;
            float e = ek[off];
            float n = ekv[off];
            ring_d[i] = e; ring_n[i] = n;
            ssd += e; ssn += n;
        }
        cs_d = pref_d - ssd;               // = cs[t0-33]
        cs_n = pref_n - ssn;
    } else {
        #pragma unroll
        for (int i = 0; i < 32; ++i) { ring_d[i] = 0.f; ring_n[i] = 0.f; }
    }

    #pragma unroll
    for (int s = 0; s < CH; ++s) {
        int t = t0 + s;
        size_t off = (size_t)t * BD + col;
        float e = ek[off];
        float n = ekv[off];
        cs_d += ring_d[s];                 // evict ek[t-32] -> cs = cs[t-32]
        cs_n += ring_n[s];
        ring_d[s] = e;
        ring_n[s] = n;
        float den = 0.f, num = 0.f;
        #pragma unroll
        for (int j4 = 0; j4 < 8; ++j4) {   // window u = t-31+j -> slot (s+1+j)&31
            float4 w4 = *(const float4*)&wl[s][j4 * 4];
            den += w4.x * ring_d[(s + 1 + j4*4 + 0) & 31];
            num += w4.x * ring_n[(s + 1 + j4*4 + 0) & 31];
            den += w4.y * ring_d[(s + 1 + j4*4 + 1) & 31];
            num += w4.y * ring_n[(s + 1 + j4*4 + 1) & 31];
            den += w4.z * ring_d[(s + 1 + j4*4 + 2) & 31];
            num += w4.z * ring_n[(s + 1 + j4*4 + 2) & 31];
            den += w4.w * ring_d[(s + 1 + j4*4 + 3) & 31];
            num += w4.w * ring_n[(s + 1 + j4*4 + 3) & 31];
        }
        if (hasp) { den += cs_d; num += cs_n; }
        float qv = q[off];
        float sig = 1.f / (1.f + expf(-qv));
        yb[off] = __float2bfloat16(sig * num / den);
    }
}

// out = yb@Wo^T + bo.  A (yb) is bf16: staged via global_load_lds;
// Wo fp32: staged via inline cvt.
__global__ __launch_bounds__(256) void gemm_out(
    const __hip_bfloat16* __restrict__ yb, const float* __restrict__ Wo,
    const float* __restrict__ bo, float* __restrict__ out)
{
    __shared__ char smem[8192];
    const int tid = threadIdx.x;
    const int lane = tid & 63;
    const int wv = tid >> 6;
    const int wave_m = wv >> 1, wave_n = wv & 1;
    const int m0 = blockIdx.y * 64, n0 = blockIdx.x * 64;
    const int kq = lane >> 4, rr = lane & 15;
    const int srow = tid & 63, skq = tid >> 6;

    f32x4 acc[2][2] = {};
    const __hip_bfloat16* Arow = yb + (size_t)(m0 + lane) * DD + wv * 8;
    char* ldsA = &smem[wv * 1024];

    for (int k0 = 0; k0 < DD; k0 += 32) {
        __syncthreads();
        async_copy16(ldsA, Arow + k0);
        stage_cvt(Wo, n0, k0, smem + 4096, srow, skq);
        __syncthreads();
        bf16x8 a0 = *(const bf16x8*)&smem[kq*1024 + (wave_m*32 +  0 + rr)*16];
        bf16x8 a1 = *(const bf16x8*)&smem[kq*1024 + (wave_m*32 + 16 + rr)*16];
        bf16x8 b0 = *(const bf16x8*)&smem[4096 + kq*1024 + (wave_n*32 +  0 + rr)*16];
        bf16x8 b1 = *(const bf16x8*)&smem[4096 + kq*1024 + (wave_n*32 + 16 + rr)*16];
        acc[0][0] = __builtin_amdgcn_mfma_f32_16x16x32_bf16(a0, b0, acc[0][0], 0, 0, 0);
        acc[0][1] = __builtin_amdgcn_mfma_f32_16x16x32_bf16(a0, b1, acc[0][1], 0, 0, 0);
        acc[1][0] = __builtin_amdgcn_mfma_f32_16x16x32_bf16(a1, b0, acc[1][0], 0, 0, 0);
        acc[1][1] = __builtin_amdgcn_mfma_f32_16x16x32_bf16(a1, b1, acc[1][1], 0, 0, 0);
    }
    #pragma unroll
    for (int ms = 0; ms < 2; ++ms)
        #pragma unroll
        for (int ns = 0; ns < 2; ++ns) {
            int n = n0 + wave_n*32 + ns*16 + rr;
            float bn = bo[n];
            #pragma unroll
            for (int r = 0; r < 4; ++r) {
                int m = m0 + wave_m*32 + ms*16 + kq*4 + r;
                out[(size_t)m * DD + n] = acc[ms][ns][r] + bn;
            }
        }
}

extern "C" void kernel_launch(void* const* d_in, const int* in_sizes, int n_in,
                              void* d_out, int out_size, void* d_ws, size_t ws_size,
                              hipStream_t stream) {
    const float* query = (const float*)d_in[0];
    const float* key   = (const float*)d_in[1];
    const float* value = (const float*)d_in[2];
    const float* Wq    = (const float*)d_in[3];
    const float* bq    = (const float*)d_in[4];
    const float* Wk    = (const float*)d_in[5];
    const float* bk    = (const float*)d_in[6];
    const float* Wv    = (const float*)d_in[7];
    const float* bv    = (const float*)d_in[8];
    const float* pb    = (const float*)d_in[9];
    const float* Wo    = (const float*)d_in[10];
    const float* bo    = (const float*)d_in[11];
    float* out = (float*)d_out;

    float* ws = (float*)d_ws;
    float* q      = ws;                       // NE
    float* ek     = ws + (size_t)NE;          // NE
    float* ekv    = ws + (size_t)2 * NE;      // NE
    float* part_d = ws + (size_t)3 * NE;      // 65536
    float* part_n = part_d + 65536;           // 65536
    __hip_bfloat16* yb = (__hip_bfloat16*)(part_n + 65536);   // NE bf16

    gemm_qkv<<<dim3(DD / 64, MR / 64, 2), 256, 0, stream>>>(
        query, key, value, Wq, Wk, Wv, bq, bk, bv,
        q, ek, ekv, part_d, part_n);

    fused_window<<<dim3(BD / 256, TT / CH), 256, 0, stream>>>(
        q, ek, ekv, part_d, part_n, pb, yb);

    gemm_out<<<dim3(DD / 64, MR / 64), 256, 0, stream>>>(yb, Wo, bo, out);
}

// Round 5
// 174.857 us; speedup vs baseline: 1.1680x; 1.1680x over previous
//
#include <hip/hip_runtime.h>
#include <hip/hip_bf16.h>

// Problem constants (AFTLocalAutoregressive): T=2048, B=2, D=512, S=32
#define TT 2048
#define BB 2
#define DD 512
#define BD (BB*DD)        // 1024 columns (b,d flattened)
#define SS 32
#define MR (TT*BB)        // 4096 GEMM rows; m = 2t + b
#define NE (TT*BB*DD)     // 2097152 elements per (T,B,D) tensor
#define CH 32             // t-chunk size for scan/window (== one 64-row m-tile)

typedef __bf16 bf16x8 __attribute__((ext_vector_type(8)));
typedef float f32x4 __attribute__((ext_vector_type(4)));

__device__ __forceinline__ void async_copy16(void* lds, const void* gptr) {
    __builtin_amdgcn_global_load_lds(
        (const __attribute__((address_space(1))) void*)gptr,
        (__attribute__((address_space(3))) void*)lds,
        16, 0, 0);
}

// fp32 -> bf16: blocks 0..6143 cover query/key/value; 6144..7167 cover 4 weights
__global__ __launch_bounds__(256) void cast_all(
    const float* __restrict__ s0, const float* __restrict__ s1, const float* __restrict__ s2,
    const float* __restrict__ w0, const float* __restrict__ w1,
    const float* __restrict__ w2, const float* __restrict__ w3,
    __hip_bfloat16* __restrict__ d0, __hip_bfloat16* __restrict__ d1, __hip_bfloat16* __restrict__ d2,
    __hip_bfloat16* __restrict__ e0, __hip_bfloat16* __restrict__ e1,
    __hip_bfloat16* __restrict__ e2, __hip_bfloat16* __restrict__ e3)
{
    int b = blockIdx.x;
    const float* s;
    __hip_bfloat16* d;
    size_t i;
    if (b < 6144) {
        int which = b >> 11;
        s = which == 0 ? s0 : (which == 1 ? s1 : s2);
        d = which == 0 ? d0 : (which == 1 ? d1 : d2);
        i = ((size_t)(b & 2047) * 256 + threadIdx.x) * 4;
    } else {
        int b2 = b - 6144;
        int which = b2 >> 8;
        s = which == 0 ? w0 : (which == 1 ? w1 : (which == 2 ? w2 : w3));
        d = which == 0 ? e0 : (which == 1 ? e1 : (which == 2 ? e2 : e3));
        i = ((size_t)(b2 & 255) * 256 + threadIdx.x) * 4;
    }
    float4 f = *(const float4*)(s + i);
    union { __hip_bfloat16 h[4]; ushort4 u; } cv;
    cv.h[0] = __float2bfloat16(f.x); cv.h[1] = __float2bfloat16(f.y);
    cv.h[2] = __float2bfloat16(f.z); cv.h[3] = __float2bfloat16(f.w);
    *(ushort4*)((unsigned short*)d + i) = cv.u;
}

// ---------------------------------------------------------------------------
// z=0: q = query@Wq^T + bq  (fp32 out)
// z=1: k,v projections fused; epilogue writes ek=exp(k), ekv=ek*v AND the
//      per-chunk column sums part_d/part_n (m-tile blockIdx.y == t-chunk).
// All operands bf16, staged via global_load_lds (k-quad-major LDS layout).
// 64x64 tile, 256 threads (4 waves, 2x2 subtiles of 16x16), BK=32.
// max_logit dropped: cancels exactly in num/den; |k|<~2.5 so exp is safe.
// ---------------------------------------------------------------------------
__global__ __launch_bounds__(256) void gemm_qkv(
    const __hip_bfloat16* __restrict__ qb, const __hip_bfloat16* __restrict__ kb,
    const __hip_bfloat16* __restrict__ vb,
    const __hip_bfloat16* __restrict__ Wqb, const __hip_bfloat16* __restrict__ Wkb,
    const __hip_bfloat16* __restrict__ Wvb,
    const float* __restrict__ bq, const float* __restrict__ bk,
    const float* __restrict__ bv,
    float* __restrict__ qout, float* __restrict__ ek, float* __restrict__ ekv,
    float* __restrict__ part_d, float* __restrict__ part_n)
{
    __shared__ char smem[16384];
    const int tid = threadIdx.x;
    const int lane = tid & 63;
    const int wv = tid >> 6;
    const int wave_m = wv >> 1, wave_n = wv & 1;
    const int m0 = blockIdx.y * 64, n0 = blockIdx.x * 64;
    const int kq = lane >> 4, rr = lane & 15;

    if (blockIdx.z == 0) {
        f32x4 acc[2][2] = {};
        const __hip_bfloat16* Arow = qb + (size_t)(m0 + lane) * DD + wv * 8;
        const __hip_bfloat16* Wrow = Wqb + (size_t)(n0 + lane) * DD + wv * 8;
        char* ldsA = &smem[wv * 1024];
        char* ldsW = &smem[4096 + wv * 1024];
        for (int k0 = 0; k0 < DD; k0 += 32) {
            __syncthreads();
            async_copy16(ldsA, Arow + k0);
            async_copy16(ldsW, Wrow + k0);
            __syncthreads();
            bf16x8 a0 = *(const bf16x8*)&smem[kq*1024 + (wave_m*32 +  0 + rr)*16];
            bf16x8 a1 = *(const bf16x8*)&smem[kq*1024 + (wave_m*32 + 16 + rr)*16];
            bf16x8 b0 = *(const bf16x8*)&smem[4096 + kq*1024 + (wave_n*32 +  0 + rr)*16];
            bf16x8 b1 = *(const bf16x8*)&smem[4096 + kq*1024 + (wave_n*32 + 16 + rr)*16];
            acc[0][0] = __builtin_amdgcn_mfma_f32_16x16x32_bf16(a0, b0, acc[0][0], 0, 0, 0);
            acc[0][1] = __builtin_amdgcn_mfma_f32_16x16x32_bf16(a0, b1, acc[0][1], 0, 0, 0);
            acc[1][0] = __builtin_amdgcn_mfma_f32_16x16x32_bf16(a1, b0, acc[1][0], 0, 0, 0);
            acc[1][1] = __builtin_amdgcn_mfma_f32_16x16x32_bf16(a1, b1, acc[1][1], 0, 0, 0);
        }
        #pragma unroll
        for (int ms = 0; ms < 2; ++ms)
            #pragma unroll
            for (int ns = 0; ns < 2; ++ns) {
                int n = n0 + wave_n*32 + ns*16 + rr;
                float bn = bq[n];
                #pragma unroll
                for (int r = 0; r < 4; ++r) {
                    int m = m0 + wave_m*32 + ms*16 + kq*4 + r;
                    qout[(size_t)m * DD + n] = acc[ms][ns][r] + bn;
                }
            }
    } else {
        f32x4 acck[2][2] = {}, accv[2][2] = {};
        const __hip_bfloat16* AKrow = kb + (size_t)(m0 + lane) * DD + wv * 8;
        const __hip_bfloat16* WKrow = Wkb + (size_t)(n0 + lane) * DD + wv * 8;
        const __hip_bfloat16* AVrow = vb + (size_t)(m0 + lane) * DD + wv * 8;
        const __hip_bfloat16* WVrow = Wvb + (size_t)(n0 + lane) * DD + wv * 8;
        char* ldsAK = &smem[wv * 1024];
        char* ldsWK = &smem[4096 + wv * 1024];
        char* ldsAV = &smem[8192 + wv * 1024];
        char* ldsWV = &smem[12288 + wv * 1024];
        for (int k0 = 0; k0 < DD; k0 += 32) {
            __syncthreads();
            async_copy16(ldsAK, AKrow + k0);
            async_copy16(ldsWK, WKrow + k0);
            async_copy16(ldsAV, AVrow + k0);
            async_copy16(ldsWV, WVrow + k0);
            __syncthreads();
            bf16x8 ak0 = *(const bf16x8*)&smem[kq*1024 + (wave_m*32 +  0 + rr)*16];
            bf16x8 ak1 = *(const bf16x8*)&smem[kq*1024 + (wave_m*32 + 16 + rr)*16];
            bf16x8 bk0 = *(const bf16x8*)&smem[4096 + kq*1024 + (wave_n*32 +  0 + rr)*16];
            bf16x8 bk1 = *(const bf16x8*)&smem[4096 + kq*1024 + (wave_n*32 + 16 + rr)*16];
            bf16x8 av0 = *(const bf16x8*)&smem[8192 + kq*1024 + (wave_m*32 +  0 + rr)*16];
            bf16x8 av1 = *(const bf16x8*)&smem[8192 + kq*1024 + (wave_m*32 + 16 + rr)*16];
            bf16x8 bv0 = *(const bf16x8*)&smem[12288 + kq*1024 + (wave_n*32 +  0 + rr)*16];
            bf16x8 bv1 = *(const bf16x8*)&smem[12288 + kq*1024 + (wave_n*32 + 16 + rr)*16];
            acck[0][0] = __builtin_amdgcn_mfma_f32_16x16x32_bf16(ak0, bk0, acck[0][0], 0, 0, 0);
            acck[0][1] = __builtin_amdgcn_mfma_f32_16x16x32_bf16(ak0, bk1, acck[0][1], 0, 0, 0);
            acck[1][0] = __builtin_amdgcn_mfma_f32_16x16x32_bf16(ak1, bk0, acck[1][0], 0, 0, 0);
            acck[1][1] = __builtin_amdgcn_mfma_f32_16x16x32_bf16(ak1, bk1, acck[1][1], 0, 0, 0);
            accv[0][0] = __builtin_amdgcn_mfma_f32_16x16x32_bf16(av0, bv0, accv[0][0], 0, 0, 0);
            accv[0][1] = __builtin_amdgcn_mfma_f32_16x16x32_bf16(av0, bv1, accv[0][1], 0, 0, 0);
            accv[1][0] = __builtin_amdgcn_mfma_f32_16x16x32_bf16(av1, bv0, accv[1][0], 0, 0, 0);
            accv[1][1] = __builtin_amdgcn_mfma_f32_16x16x32_bf16(av1, bv1, accv[1][1], 0, 0, 0);
        }
        // epilogue: ek/ekv stores + per-chunk column sums (split by b = m&1 = r&1)
        float sd[2][2] = {{0.f,0.f},{0.f,0.f}};   // [ns][parity]
        float sn[2][2] = {{0.f,0.f},{0.f,0.f}};
        #pragma unroll
        for (int ms = 0; ms < 2; ++ms)
            #pragma unroll
            for (int ns = 0; ns < 2; ++ns) {
                int n = n0 + wave_n*32 + ns*16 + rr;
                float bkn = bk[n], bvn = bv[n];
                #pragma unroll
                for (int r = 0; r < 4; ++r) {
                    int m = m0 + wave_m*32 + ms*16 + kq*4 + r;
                    float e  = expf(acck[ms][ns][r] + bkn);
                    float nv = e * (accv[ms][ns][r] + bvn);
                    ek[(size_t)m * DD + n]  = e;
                    ekv[(size_t)m * DD + n] = nv;
                    sd[ns][r & 1] += e;
                    sn[ns][r & 1] += nv;
                }
            }
        // reduce over the 4 kq groups (lane bits 4,5)
        #pragma unroll
        for (int ns = 0; ns < 2; ++ns)
            #pragma unroll
            for (int par = 0; par < 2; ++par) {
                sd[ns][par] += __shfl_xor(sd[ns][par], 16, 64);
                sd[ns][par] += __shfl_xor(sd[ns][par], 32, 64);
                sn[ns][par] += __shfl_xor(sn[ns][par], 16, 64);
                sn[ns][par] += __shfl_xor(sn[ns][par], 32, 64);
            }
        __syncthreads();                       // smem free for reuse
        float* red = (float*)smem;             // red[which(4)][wave_m(2)][64]
        if (lane < 16) {
            #pragma unroll
            for (int ns = 0; ns < 2; ++ns) {
                int c = wave_n*32 + ns*16 + rr;
                red[(0*2 + wave_m)*64 + c] = sd[ns][0];
                red[(1*2 + wave_m)*64 + c] = sd[ns][1];
                red[(2*2 + wave_m)*64 + c] = sn[ns][0];
                red[(3*2 + wave_m)*64 + c] = sn[ns][1];
            }
        }
        __syncthreads();
        {
            int which = tid >> 6;              // 0: d,b0  1: d,b1  2: n,b0  3: n,b1
            int c = tid & 63;
            float s = red[(which*2 + 0)*64 + c] + red[(which*2 + 1)*64 + c];
            int b = which & 1;
            float* dst = (which < 2) ? part_d : part_n;
            dst[(size_t)blockIdx.y * BD + b*512 + n0 + c] = s;
        }
    }
}

// Fused: chunk-prefix seed + streaming scan + sliding window (register ring)
// + sigmoid gate + bf16 cast.  grid (BD/256, T/CH) = (4, 64).
__global__ __launch_bounds__(256) void fused_window(
    const float* __restrict__ q, const float* __restrict__ ek,
    const float* __restrict__ ekv, const float* __restrict__ part_d,
    const float* __restrict__ part_n, const float* __restrict__ pb,
    __hip_bfloat16* __restrict__ yb)
{
    __shared__ float wl[CH][SS];          // 4 KB: wexp for this t-chunk
    const int tid = threadIdx.x;
    const int col = blockIdx.x * 256 + tid;
    const int chunk = blockIdx.y;
    const int t0 = chunk * CH;

    // w[t_local][j] = valid * exp(pb[t, t-31+j])
    #pragma unroll
    for (int i = 0; i < (CH * SS) / 256; ++i) {
        int idx = tid + i * 256;
        int tl = idx >> 5, j = idx & 31;
        int t = t0 + tl;
        int u = t - (SS - 1) + j;
        float w = 0.f;
        if (u >= 0) w = expf(pb[(size_t)t * TT + u]);
        wl[tl][j] = w;
    }
    __syncthreads();

    float ring_d[32], ring_n[32];
    float cs_d = 0.f, cs_n = 0.f;
    const bool hasp = (chunk > 0);
    if (hasp) {
        float pref_d = 0.f, pref_n = 0.f;
        for (int p = 0; p < chunk; ++p) {
            pref_d += part_d[(size_t)p * BD + col];
            pref_n += part_n[(size_t)p * BD + col];
        }
        float ssd = 0.f, ssn = 0.f;
        #pragma unroll
        for (int i = 0; i < 32; ++i) {     // prefill ring with t0-32 .. t0-1
            size_t off = (size_t)(t0 - 32 + i) * BD + col;
            float e = ek[off];
            float n = ekv[off];
            ring_d[i] = e; ring_n[i] = n;
            ssd += e; ssn += n;
        }
        cs_d = pref_d - ssd;               // = cs[t0-33]
        cs_n = pref_n - ssn;
    } else {
        #pragma unroll
        for (int i = 0; i < 32; ++i) { ring_d[i] = 0.f; ring_n[i] = 0.f; }
    }

    #pragma unroll
    for (int s = 0; s < CH; ++s) {
        int t = t0 + s;
        size_t off = (size_t)t * BD + col;
        float e = ek[off];
        float n = ekv[off];
        cs_d += ring_d[s];                 // evict ek[t-32] -> cs = cs[t-32]
        cs_n += ring_n[s];
        ring_d[s] = e;
        ring_n[s] = n;
        float den = 0.f, num = 0.f;
        #pragma unroll
        for (int j4 = 0; j4 < 8; ++j4) {   // window u = t-31+j -> slot (s+1+j)&31
            float4 w4 = *(const float4*)&wl[s][j4 * 4];
            den += w4.x * ring_d[(s + 1 + j4*4 + 0) & 31];
            num += w4.x * ring_n[(s + 1 + j4*4 + 0) & 31];
            den += w4.y * ring_d[(s + 1 + j4*4 + 1) & 31];
            num += w4.y * ring_n[(s + 1 + j4*4 + 1) & 31];
            den += w4.z * ring_d[(s + 1 + j4*4 + 2) & 31];
            num += w4.z * ring_n[(s + 1 + j4*4 + 2) & 31];
            den += w4.w * ring_d[(s + 1 + j4*4 + 3) & 31];
            num += w4.w * ring_n[(s + 1 + j4*4 + 3) & 31];
        }
        if (hasp) { den += cs_d; num += cs_n; }
        float qv = q[off];
        float sig = 1.f / (1.f + expf(-qv));
        yb[off] = __float2bfloat16(sig * num / den);
    }
}

// out = yb@Wo^T + bo.  Both operands bf16, staged via global_load_lds.
__global__ __launch_bounds__(256) void gemm_out(
    const __hip_bfloat16* __restrict__ yb, const __hip_bfloat16* __restrict__ Wob,
    const float* __restrict__ bo, float* __restrict__ out)
{
    __shared__ char smem[8192];
    const int tid = threadIdx.x;
    const int lane = tid & 63;
    const int wv = tid >> 6;
    const int wave_m = wv >> 1, wave_n = wv & 1;
    const int m0 = blockIdx.y * 64, n0 = blockIdx.x * 64;
    const int kq = lane >> 4, rr = lane & 15;

    f32x4 acc[2][2] = {};
    const __hip_bfloat16* Arow = yb + (size_t)(m0 + lane) * DD + wv * 8;
    const __hip_bfloat16* Wrow = Wob + (size_t)(n0 + lane) * DD + wv * 8;
    char* ldsA = &smem[wv * 1024];
    char* ldsW = &smem[4096 + wv * 1024];

    for (int k0 = 0; k0 < DD; k0 += 32) {
        __syncthreads();
        async_copy16(ldsA, Arow + k0);
        async_copy16(ldsW, Wrow + k0);
        __syncthreads();
        bf16x8 a0 = *(const bf16x8*)&smem[kq*1024 + (wave_m*32 +  0 + rr)*16];
        bf16x8 a1 = *(const bf16x8*)&smem[kq*1024 + (wave_m*32 + 16 + rr)*16];
        bf16x8 b0 = *(const bf16x8*)&smem[4096 + kq*1024 + (wave_n*32 +  0 + rr)*16];
        bf16x8 b1 = *(const bf16x8*)&smem[4096 + kq*1024 + (wave_n*32 + 16 + rr)*16];
        acc[0][0] = __builtin_amdgcn_mfma_f32_16x16x32_bf16(a0, b0, acc[0][0], 0, 0, 0);
        acc[0][1] = __builtin_amdgcn_mfma_f32_16x16x32_bf16(a0, b1, acc[0][1], 0, 0, 0);
        acc[1][0] = __builtin_amdgcn_mfma_f32_16x16x32_bf16(a1, b0, acc[1][0], 0, 0, 0);
        acc[1][1] = __builtin_amdgcn_mfma_f32_16x16x32_bf16(a1, b1, acc[1][1], 0, 0, 0);
    }
    #pragma unroll
    for (int ms = 0; ms < 2; ++ms)
        #pragma unroll
        for (int ns = 0; ns < 2; ++ns) {
            int n = n0 + wave_n*32 + ns*16 + rr;
            float bn = bo[n];
            #pragma unroll
            for (int r = 0; r < 4; ++r) {
                int m = m0 + wave_m*32 + ms*16 + kq*4 + r;
                out[(size_t)m * DD + n] = acc[ms][ns][r] + bn;
            }
        }
}

extern "C" void kernel_launch(void* const* d_in, const int* in_sizes, int n_in,
                              void* d_out, int out_size, void* d_ws, size_t ws_size,
                              hipStream_t stream) {
    const float* query = (const float*)d_in[0];
    const float* key   = (const float*)d_in[1];
    const float* value = (const float*)d_in[2];
    const float* Wq    = (const float*)d_in[3];
    const float* bq    = (const float*)d_in[4];
    const float* Wk    = (const float*)d_in[5];
    const float* bk    = (const float*)d_in[6];
    const float* Wv    = (const float*)d_in[7];
    const float* bv    = (const float*)d_in[8];
    const float* pb    = (const float*)d_in[9];
    const float* Wo    = (const float*)d_in[10];
    const float* bo    = (const float*)d_in[11];
    float* out = (float*)d_out;

    float* ws = (float*)d_ws;
    float* q      = ws;                       // NE
    float* ek     = ws + (size_t)NE;          // NE
    float* ekv    = ws + (size_t)2 * NE;      // NE
    float* part_d = ws + (size_t)3 * NE;      // 65536
    float* part_n = part_d + 65536;           // 65536
    __hip_bfloat16* bfb = (__hip_bfloat16*)(part_n + 65536);
    __hip_bfloat16* qb  = bfb;                // NE each
    __hip_bfloat16* kb  = bfb + (size_t)NE;
    __hip_bfloat16* vb  = bfb + (size_t)2 * NE;
    __hip_bfloat16* yb  = bfb + (size_t)3 * NE;
    __hip_bfloat16* Wqb = bfb + (size_t)4 * NE;   // 262144 each
    __hip_bfloat16* Wkb = Wqb + 262144;
    __hip_bfloat16* Wvb = Wkb + 262144;
    __hip_bfloat16* Wob = Wvb + 262144;

    cast_all<<<7168, 256, 0, stream>>>(query, key, value, Wq, Wk, Wv, Wo,
                                       qb, kb, vb, Wqb, Wkb, Wvb, Wob);

    gemm_qkv<<<dim3(DD / 64, MR / 64, 2), 256, 0, stream>>>(
        qb, kb, vb, Wqb, Wkb, Wvb, bq, bk, bv,
        q, ek, ekv, part_d, part_n);

    fused_window<<<dim3(BD / 256, TT / CH), 256, 0, stream>>>(
        q, ek, ekv, part_d, part_n, pb, yb);

    gemm_out<<<dim3(DD / 64, MR / 64), 256, 0, stream>>>(yb, Wob, bo, out);
}